// Round 10
// baseline (334.145 us; speedup 1.0000x reference)
//
#include <hip/hip_runtime.h>
#include <math.h>

// Problem shapes
constexpr int B = 4, H = 16, S = 1024, D = 256, P = 64;
constexpr long long N_ROWS = (long long)B * H * S;            // 65536
// Output segment offsets (floats, concatenated in return order)
constexpr long long OFF_RT = 0;                               // routing_scores
constexpr long long SZ_RT  = N_ROWS;                          // 65536
constexpr long long OFF_OR = OFF_RT + SZ_RT;                  // optimal_routes
constexpr long long SZ_OR  = N_ROWS * (long long)S;           // 67108864
constexpr long long OFF_TW = OFF_OR + SZ_OR;                  // transfer_weights
constexpr long long SZ_TW  = 16LL * 64 * 64;                  // 65536
constexpr long long OFF_PS = OFF_TW + SZ_TW;                  // pattern_scores

typedef _Float16 half8   __attribute__((ext_vector_type(8)));
typedef _Float16 half4v  __attribute__((ext_vector_type(4)));
typedef float    floatx4 __attribute__((ext_vector_type(4)));

// LDS row stride for B tiles: 256 + 8 halves (16-B pad) keeps ds_read_b128
// 16-B aligned and balances the 16-lane fragment reads across banks.
constexpr int BSTRIDE = 264;

// ---------------------------------------------------------------------------
// Kernel 1 (fused fill + prep): 16384 route blocks (4 plain contiguous
// float4 stores per thread, 64 KB per block — value depends only on tid;
// R5 lesson: NT + huge strides regress, so stores stay plain and block-local),
// 128 small-segment blocks, 16 normalize blocks.
__global__ __launch_bounds__(256) void k_fill_prep(
        floatx4* __restrict__ routes,
        const floatx4* __restrict__ tw,
        float* __restrict__ out,
        const float* __restrict__ pat,
        _Float16* __restrict__ pnh,
        _Float16* __restrict__ pnl) {
    long long blk = blockIdx.x;
    int t = threadIdx.x;
    if (blk < 16384) {
        // j0 = ((blk*1024 + i*256 + t) * 4) & 1023 = 4t  (blk,i terms = 0 mod 1024)
        float b0 = (float)(t * 4) * (-0.0009765625f);
        floatx4 v;
        v.x = b0;
        v.y = b0 - 0.0009765625f;
        v.z = b0 - 0.001953125f;
        v.w = b0 - 0.0029296875f;
        floatx4* dst = routes + blk * 1024 + t;
        #pragma unroll
        for (int i = 0; i < 4; ++i) {
            dst[i * 256] = v;                        // wave inst: 1 KB contiguous
        }
    } else if (blk < 16384 + 128) {
        int i = (int)(blk - 16384) * 256 + t;        // 0..32767
        constexpr int Q = (int)SZ_RT / 4;            // 16384 float4 / segment
        if (i < Q) {
            floatx4 v = { 0.0009765625f, 0.0009765625f,
                          0.0009765625f, 0.0009765625f };
            ((floatx4*)(out + OFF_RT))[i] = v;
        } else {
            ((floatx4*)(out + OFF_TW))[i - Q] = tw[i - Q];
        }
    } else {
        // normalize: 16 blocks x 4 waves, one pattern per wave; fold 1/T=10,
        // split into f16 hi/lo (a = hi + lo) for split-precision MFMA.
        int p    = (int)(blk - 16384 - 128) * 4 + (t >> 6);
        int lane = t & 63;
        const floatx4* src = (const floatx4*)(pat + (long long)p * D);
        floatx4 v = src[lane];
        float ss = v.x * v.x + v.y * v.y + v.z * v.z + v.w * v.w;
        #pragma unroll
        for (int m = 1; m < 64; m <<= 1) ss += __shfl_xor(ss, m, 64);
        float scale = 10.0f / fmaxf(sqrtf(ss), 1e-12f);
        float a[4] = { v.x * scale, v.y * scale, v.z * scale, v.w * scale };
        half4v hh, ll;
        #pragma unroll
        for (int j = 0; j < 4; ++j) {
            _Float16 h = (_Float16)a[j];
            hh[j] = h;
            ll[j] = (_Float16)(a[j] - (float)h);
        }
        *(half4v*)(pnh + (long long)p * D + lane * 4) = hh;
        *(half4v*)(pnl + (long long)p * D + lane * 4) = ll;
    }
}

// ---------------------------------------------------------------------------
// Kernel 2 (gemm, unchanged from R8): sims = states @ pn^T via f16
// split-precision MFMA + row softmax. Wave tile 32 rows x 64 patterns
// (128-row blocks, 512 blocks); B staged in LDS once per block (R7 win);
// each B-fragment pair feeds 6 MFMAs (R8 win). HBM-bound at ~20 us
// (floor 12.5); compute pipes are ~15x slack.
__global__ __launch_bounds__(256) void k_gemm_mfma(
        const float* __restrict__ states,
        const _Float16* __restrict__ pnh,
        const _Float16* __restrict__ pnl,
        float* __restrict__ out_ps) {
    __shared__ _Float16 smem[2 * P * BSTRIDE];       // Bh then Bl
    _Float16* smH = smem;
    _Float16* smL = smem + P * BSTRIDE;

    int tid  = threadIdx.x;
    // --- Phase 0: stage B into LDS (coalesced) -----------------------------
    {
        const half8* gh = (const half8*)pnh;         // 2048 x 16 B chunks
        const half8* gl = (const half8*)pnl;
        #pragma unroll
        for (int it = 0; it < 8; ++it) {
            int idx = it * 256 + tid;
            int row = idx >> 5;                      // pattern row
            int c8  = idx & 31;                      // 8-half chunk in row
            *(half8*)&smH[row * BSTRIDE + c8 * 8] = gh[idx];
            *(half8*)&smL[row * BSTRIDE + c8 * 8] = gl[idx];
        }
    }
    __syncthreads();

    int wave = tid >> 6;
    int lane = tid & 63;
    int q    = lane >> 4;                  // quad 0..3
    int m    = lane & 15;
    long long row0 = (long long)blockIdx.x * 128 + wave * 32;
    const float* __restrict__ arow0 = states + (row0 + m) * D + q * 8;
    const float* __restrict__ arow1 = arow0 + 16 * D;

    floatx4 acc0[4] = {floatx4{0,0,0,0}, floatx4{0,0,0,0},
                       floatx4{0,0,0,0}, floatx4{0,0,0,0}};
    floatx4 acc1[4] = {floatx4{0,0,0,0}, floatx4{0,0,0,0},
                       floatx4{0,0,0,0}, floatx4{0,0,0,0}};

    float4 n0 = *(const float4*)(arow0);
    float4 n1 = *(const float4*)(arow0 + 4);
    float4 n2 = *(const float4*)(arow1);
    float4 n3 = *(const float4*)(arow1 + 4);
    #pragma unroll
    for (int kk = 0; kk < 8; ++kk) {
        float av0[8] = { n0.x, n0.y, n0.z, n0.w, n1.x, n1.y, n1.z, n1.w };
        float av1[8] = { n2.x, n2.y, n2.z, n2.w, n3.x, n3.y, n3.z, n3.w };
        if (kk < 7) {                                 // prefetch next A chunks
            n0 = *(const float4*)(arow0 + (kk + 1) * 32);
            n1 = *(const float4*)(arow0 + (kk + 1) * 32 + 4);
            n2 = *(const float4*)(arow1 + (kk + 1) * 32);
            n3 = *(const float4*)(arow1 + (kk + 1) * 32 + 4);
        }
        half8 ah0, al0, ah1, al1;
        #pragma unroll
        for (int j = 0; j < 8; ++j) {
            _Float16 h0 = (_Float16)av0[j];
            ah0[j] = h0;
            al0[j] = (_Float16)(av0[j] - (float)h0);
            _Float16 h1 = (_Float16)av1[j];
            ah1[j] = h1;
            al1[j] = (_Float16)(av1[j] - (float)h1);
        }
        #pragma unroll
        for (int t = 0; t < 4; ++t) {
            int boff = (t * 16 + m) * BSTRIDE + kk * 32 + q * 8;
            half8 bh = *(const half8*)&smH[boff];
            half8 bl = *(const half8*)&smL[boff];
            acc0[t] = __builtin_amdgcn_mfma_f32_16x16x32_f16(ah0, bh, acc0[t], 0, 0, 0);
            acc0[t] = __builtin_amdgcn_mfma_f32_16x16x32_f16(al0, bh, acc0[t], 0, 0, 0);
            acc0[t] = __builtin_amdgcn_mfma_f32_16x16x32_f16(ah0, bl, acc0[t], 0, 0, 0);
            acc1[t] = __builtin_amdgcn_mfma_f32_16x16x32_f16(ah1, bh, acc1[t], 0, 0, 0);
            acc1[t] = __builtin_amdgcn_mfma_f32_16x16x32_f16(al1, bh, acc1[t], 0, 0, 0);
            acc1[t] = __builtin_amdgcn_mfma_f32_16x16x32_f16(ah1, bl, acc1[t], 0, 0, 0);
        }
    }

    // Row softmax per row set: row = q*4 + r lives in the 16 lanes sharing q
    // (shuffle masks 1..8 stay in-group); lane holds 4 cols (one per N-tile).
    #pragma unroll
    for (int set = 0; set < 2; ++set) {
        floatx4* acc = set ? acc1 : acc0;
        long long rbase = row0 + set * 16;
        #pragma unroll
        for (int r = 0; r < 4; ++r) {
            float mx = fmaxf(fmaxf(acc[0][r], acc[1][r]),
                             fmaxf(acc[2][r], acc[3][r]));
            #pragma unroll
            for (int msk = 1; msk < 16; msk <<= 1)
                mx = fmaxf(mx, __shfl_xor(mx, msk, 64));
            float e[4];
            float s = 0.0f;
            #pragma unroll
            for (int t = 0; t < 4; ++t) { e[t] = __expf(acc[t][r] - mx); s += e[t]; }
            #pragma unroll
            for (int msk = 1; msk < 16; msk <<= 1) s += __shfl_xor(s, msk, 64);
            float inv = 1.0f / s;
            long long row = rbase + q * 4 + r;
            #pragma unroll
            for (int t = 0; t < 4; ++t) {
                out_ps[row * P + t * 16 + m] = e[t] * inv;
            }
        }
    }
}

// ---------------------------------------------------------------------------
extern "C" void kernel_launch(void* const* d_in, const int* in_sizes, int n_in,
                              void* d_out, int out_size, void* d_ws, size_t ws_size,
                              hipStream_t stream) {
    const float* states   = (const float*)d_in[0];   // (4,16,1024,256) fp32
    const float* patterns = (const float*)d_in[1];   // (64,256) fp32
    const float* transfer = (const float*)d_in[2];   // (16,64,64) fp32
    float* out = (float*)d_out;
    _Float16* pnh = (_Float16*)d_ws;                 // 64*256 halves = 32 KB
    _Float16* pnl = pnh + P * D;                     // +32 KB

    k_fill_prep<<<dim3(16384 + 128 + 16), dim3(256), 0, stream>>>(
        (floatx4*)(out + OFF_OR), (const floatx4*)transfer, out,
        patterns, pnh, pnl);

    k_gemm_mfma<<<dim3(512), dim3(256), 0, stream>>>(states, pnh, pnl, out + OFF_PS);
}

// Round 11
// 326.406 us; speedup vs baseline: 1.0237x; 1.0237x over previous
//
#include <hip/hip_runtime.h>
#include <math.h>

// Problem shapes
constexpr int B = 4, H = 16, S = 1024, D = 256, P = 64;
constexpr long long N_ROWS = (long long)B * H * S;            // 65536
// Output segment offsets (floats, concatenated in return order)
constexpr long long OFF_RT = 0;                               // routing_scores
constexpr long long SZ_RT  = N_ROWS;                          // 65536
constexpr long long OFF_OR = OFF_RT + SZ_RT;                  // optimal_routes
constexpr long long SZ_OR  = N_ROWS * (long long)S;           // 67108864
constexpr long long OFF_TW = OFF_OR + SZ_OR;                  // transfer_weights
constexpr long long SZ_TW  = 16LL * 64 * 64;                  // 65536
constexpr long long OFF_PS = OFF_TW + SZ_TW;                  // pattern_scores

typedef _Float16 half8   __attribute__((ext_vector_type(8)));
typedef _Float16 half4v  __attribute__((ext_vector_type(4)));
typedef float    floatx4 __attribute__((ext_vector_type(4)));

// LDS row stride for B tiles: 256 + 8 halves (16-B pad) keeps ds_read_b128
// 16-B aligned and balances the 16-lane fragment reads across banks.
constexpr int BSTRIDE = 264;

// ---------------------------------------------------------------------------
// Kernel 1 (fused fill + prep), R8's exact known-good structure:
// 65536 route blocks (ONE plain contiguous float4 store per thread — R5/R9
// lesson: any thread-level store striding, NT or plain, fragments the write
// stream and regresses 5-20%; consecutive blocks -> consecutive 1 KB segments
// is what the runtime's 6.4 TB/s fill does), 128 small-segment blocks,
// 16 normalize blocks.
__global__ __launch_bounds__(256) void k_fill_prep(
        floatx4* __restrict__ routes,
        const floatx4* __restrict__ tw,
        float* __restrict__ out,
        const float* __restrict__ pat,
        _Float16* __restrict__ pnh,
        _Float16* __restrict__ pnl) {
    long long blk = blockIdx.x;
    int t = threadIdx.x;
    if (blk < 65536) {
        long long i = blk * 256 + t;
        int j0 = (int)((i << 2) & (S - 1));          // 1024-periodic column
        float b0 = (float)j0 * (-0.0009765625f);
        floatx4 v;
        v.x = b0;
        v.y = b0 - 0.0009765625f;
        v.z = b0 - 0.001953125f;
        v.w = b0 - 0.0029296875f;
        routes[i] = v;
    } else if (blk < 65536 + 128) {
        int i = (int)(blk - 65536) * 256 + t;        // 0..32767
        constexpr int Q = (int)SZ_RT / 4;            // 16384 float4 / segment
        if (i < Q) {
            floatx4 v = { 0.0009765625f, 0.0009765625f,
                          0.0009765625f, 0.0009765625f };
            ((floatx4*)(out + OFF_RT))[i] = v;
        } else {
            ((floatx4*)(out + OFF_TW))[i - Q] = tw[i - Q];
        }
    } else {
        // normalize: 16 blocks x 4 waves, one pattern per wave; fold 1/T=10,
        // split into f16 hi/lo (a = hi + lo) for split-precision MFMA.
        int p    = (int)(blk - 65536 - 128) * 4 + (t >> 6);
        int lane = t & 63;
        const floatx4* src = (const floatx4*)(pat + (long long)p * D);
        floatx4 v = src[lane];
        float ss = v.x * v.x + v.y * v.y + v.z * v.z + v.w * v.w;
        #pragma unroll
        for (int m = 1; m < 64; m <<= 1) ss += __shfl_xor(ss, m, 64);
        float scale = 10.0f / fmaxf(sqrtf(ss), 1e-12f);
        float a[4] = { v.x * scale, v.y * scale, v.z * scale, v.w * scale };
        half4v hh, ll;
        #pragma unroll
        for (int j = 0; j < 4; ++j) {
            _Float16 h = (_Float16)a[j];
            hh[j] = h;
            ll[j] = (_Float16)(a[j] - (float)h);
        }
        *(half4v*)(pnh + (long long)p * D + lane * 4) = hh;
        *(half4v*)(pnl + (long long)p * D + lane * 4) = ll;
    }
}

// ---------------------------------------------------------------------------
// Kernel 2 (gemm, unchanged from R8 best): sims = states @ pn^T via f16
// split-precision MFMA + row softmax. Wave tile 32 rows x 64 patterns
// (128-row blocks, 512 blocks); B staged in LDS once per block (R7 win);
// each B-fragment pair feeds 6 MFMAs (R8 win). HBM-bound at ~20 us
// (floor 12.5); compute pipes are ~15x slack.
__global__ __launch_bounds__(256) void k_gemm_mfma(
        const float* __restrict__ states,
        const _Float16* __restrict__ pnh,
        const _Float16* __restrict__ pnl,
        float* __restrict__ out_ps) {
    __shared__ _Float16 smem[2 * P * BSTRIDE];       // Bh then Bl
    _Float16* smH = smem;
    _Float16* smL = smem + P * BSTRIDE;

    int tid  = threadIdx.x;
    // --- Phase 0: stage B into LDS (coalesced) -----------------------------
    {
        const half8* gh = (const half8*)pnh;         // 2048 x 16 B chunks
        const half8* gl = (const half8*)pnl;
        #pragma unroll
        for (int it = 0; it < 8; ++it) {
            int idx = it * 256 + tid;
            int row = idx >> 5;                      // pattern row
            int c8  = idx & 31;                      // 8-half chunk in row
            *(half8*)&smH[row * BSTRIDE + c8 * 8] = gh[idx];
            *(half8*)&smL[row * BSTRIDE + c8 * 8] = gl[idx];
        }
    }
    __syncthreads();

    int wave = tid >> 6;
    int lane = tid & 63;
    int q    = lane >> 4;                  // quad 0..3
    int m    = lane & 15;
    long long row0 = (long long)blockIdx.x * 128 + wave * 32;
    const float* __restrict__ arow0 = states + (row0 + m) * D + q * 8;
    const float* __restrict__ arow1 = arow0 + 16 * D;

    floatx4 acc0[4] = {floatx4{0,0,0,0}, floatx4{0,0,0,0},
                       floatx4{0,0,0,0}, floatx4{0,0,0,0}};
    floatx4 acc1[4] = {floatx4{0,0,0,0}, floatx4{0,0,0,0},
                       floatx4{0,0,0,0}, floatx4{0,0,0,0}};

    float4 n0 = *(const float4*)(arow0);
    float4 n1 = *(const float4*)(arow0 + 4);
    float4 n2 = *(const float4*)(arow1);
    float4 n3 = *(const float4*)(arow1 + 4);
    #pragma unroll
    for (int kk = 0; kk < 8; ++kk) {
        float av0[8] = { n0.x, n0.y, n0.z, n0.w, n1.x, n1.y, n1.z, n1.w };
        float av1[8] = { n2.x, n2.y, n2.z, n2.w, n3.x, n3.y, n3.z, n3.w };
        if (kk < 7) {                                 // prefetch next A chunks
            n0 = *(const float4*)(arow0 + (kk + 1) * 32);
            n1 = *(const float4*)(arow0 + (kk + 1) * 32 + 4);
            n2 = *(const float4*)(arow1 + (kk + 1) * 32);
            n3 = *(const float4*)(arow1 + (kk + 1) * 32 + 4);
        }
        half8 ah0, al0, ah1, al1;
        #pragma unroll
        for (int j = 0; j < 8; ++j) {
            _Float16 h0 = (_Float16)av0[j];
            ah0[j] = h0;
            al0[j] = (_Float16)(av0[j] - (float)h0);
            _Float16 h1 = (_Float16)av1[j];
            ah1[j] = h1;
            al1[j] = (_Float16)(av1[j] - (float)h1);
        }
        #pragma unroll
        for (int t = 0; t < 4; ++t) {
            int boff = (t * 16 + m) * BSTRIDE + kk * 32 + q * 8;
            half8 bh = *(const half8*)&smH[boff];
            half8 bl = *(const half8*)&smL[boff];
            acc0[t] = __builtin_amdgcn_mfma_f32_16x16x32_f16(ah0, bh, acc0[t], 0, 0, 0);
            acc0[t] = __builtin_amdgcn_mfma_f32_16x16x32_f16(al0, bh, acc0[t], 0, 0, 0);
            acc0[t] = __builtin_amdgcn_mfma_f32_16x16x32_f16(ah0, bl, acc0[t], 0, 0, 0);
            acc1[t] = __builtin_amdgcn_mfma_f32_16x16x32_f16(ah1, bh, acc1[t], 0, 0, 0);
            acc1[t] = __builtin_amdgcn_mfma_f32_16x16x32_f16(al1, bh, acc1[t], 0, 0, 0);
            acc1[t] = __builtin_amdgcn_mfma_f32_16x16x32_f16(ah1, bl, acc1[t], 0, 0, 0);
        }
    }

    // Row softmax per row set: row = q*4 + r lives in the 16 lanes sharing q
    // (shuffle masks 1..8 stay in-group); lane holds 4 cols (one per N-tile).
    #pragma unroll
    for (int set = 0; set < 2; ++set) {
        floatx4* acc = set ? acc1 : acc0;
        long long rbase = row0 + set * 16;
        #pragma unroll
        for (int r = 0; r < 4; ++r) {
            float mx = fmaxf(fmaxf(acc[0][r], acc[1][r]),
                             fmaxf(acc[2][r], acc[3][r]));
            #pragma unroll
            for (int msk = 1; msk < 16; msk <<= 1)
                mx = fmaxf(mx, __shfl_xor(mx, msk, 64));
            float e[4];
            float s = 0.0f;
            #pragma unroll
            for (int t = 0; t < 4; ++t) { e[t] = __expf(acc[t][r] - mx); s += e[t]; }
            #pragma unroll
            for (int msk = 1; msk < 16; msk <<= 1) s += __shfl_xor(s, msk, 64);
            float inv = 1.0f / s;
            long long row = rbase + q * 4 + r;
            #pragma unroll
            for (int t = 0; t < 4; ++t) {
                out_ps[row * P + t * 16 + m] = e[t] * inv;
            }
        }
    }
}

// ---------------------------------------------------------------------------
extern "C" void kernel_launch(void* const* d_in, const int* in_sizes, int n_in,
                              void* d_out, int out_size, void* d_ws, size_t ws_size,
                              hipStream_t stream) {
    const float* states   = (const float*)d_in[0];   // (4,16,1024,256) fp32
    const float* patterns = (const float*)d_in[1];   // (64,256) fp32
    const float* transfer = (const float*)d_in[2];   // (16,64,64) fp32
    float* out = (float*)d_out;
    _Float16* pnh = (_Float16*)d_ws;                 // 64*256 halves = 32 KB
    _Float16* pnl = pnh + P * D;                     // +32 KB

    k_fill_prep<<<dim3(65536 + 128 + 16), dim3(256), 0, stream>>>(
        (floatx4*)(out + OFF_OR), (const floatx4*)transfer, out,
        patterns, pnh, pnl);

    k_gemm_mfma<<<dim3(512), dim3(256), 0, stream>>>(states, pnh, pnl, out + OFF_PS);
}